// Round 2
// baseline (190.227 us; speedup 1.0000x reference)
//
#include <hip/hip_runtime.h>

// YOLOv1-style loss: S=7, B=2, C=20, L=49, n=16384.
// preds row: [ pcls: 980 | pconf: 98 | pbox: 392 ] = 1470 floats
// labels row: L * [ obj(1) | tcls(20) | tbox(4) ] = 1225 floats
// Weights: NOOBJ=0.5, OBJ=0.5, CLS=0.5, COORD=2.5
//
// R9: single-chain branch-free streaming. Evidence: R8 total 185us with
// fixed harness cost ~135-140us (385MB re-poison fills @56.5us each) ->
// loss kernel ~46us vs 17us floor on ~105MB gated traffic = 2.3 TB/s
// delivered = latency-bound. Cause: two SERIALIZED cold-miss chains per
// wave (stage labels -> LDS, then objf-gated pcls/pbox loads). Fix:
// issue ALL loads back-to-back at wave start (labels via
// global_load_lds width=16, m97 pattern, no VGPR roundtrip; pcls/pbox/
// conf unconditional float2s), ONE vmcnt(0), branch-free compute with
// select. Traffic ~105->~177MB (+28us floor) but one miss chain instead
// of two; ~200B/lane independent loads x 20 waves/CU = ~250KB/CU in
// flight >> BW*latency product -> should be HBM-bound ~30us.

#define L_CELLS 49
#define PRED_ROW 1470
#define LAB_ROW 1225
#define CONF_BASE 980
#define BOX_BASE 1078
#define W_NOOBJ 0.5f
#define W_OBJ 0.5f
#define W_CLS 0.5f
#define W_COORD 2.5f
#define INV_S (1.0f / 7.0f)

#define LAB_SLOTS 308  // ceil((3 + 1225)/4)
#define WAVE_SLOTS 310 // +pad

typedef int __attribute__((address_space(1))) as1_int;
typedef int __attribute__((address_space(3))) as3_int;

__global__ __launch_bounds__(256, 5) void yolo_loss_kernel(
    const float* __restrict__ preds, const float* __restrict__ labels,
    float* __restrict__ ws) {
  __shared__ float4 st[4][WAVE_SLOTS];  // 19840 B/block

  const int tid = threadIdx.x;
  const int w = tid >> 6;
  const int lane = tid & 63;
  const int s = blockIdx.x * 4 + w;
  float4* stw = st[w];

  // ---- stage labels row direct to LDS (global_load_lds width=16).
  // Dest is wave-uniform base + lane*16 (linear slots, matches layout).
  // Align-down; <=16B page-safe overread on final row (R5-R8 verified).
  size_t g0 = (size_t)s * LAB_ROW;
  size_t ga = g0 & ~(size_t)3;
  int loff = (int)(g0 - ga);
#pragma unroll
  for (int r = 0; r < 5; ++r) {
    int i = lane + 64 * r;
    if (i < LAB_SLOTS) {
      __builtin_amdgcn_global_load_lds(
          (const as1_int*)(labels + ga + 4 * (size_t)i),
          (as3_int*)((float*)stw + 256 * r), 16, 0, 0);
    }
  }

  const float* rp = preds + (size_t)s * PRED_ROW;

  // ---- issue ALL pred loads unconditionally (lanes < 49), same chain ----
  float2 cf = make_float2(0.f, 0.f);
  float2 pc[10];
  float2 bq[4];
  if (lane < L_CELLS) {
    const int l = lane;
    cf = *(const float2*)(rp + CONF_BASE + 2 * l);            // 8B-aligned
#pragma unroll
    for (int k = 0; k < 10; ++k)
      pc[k] = *(const float2*)(rp + 20 * l + 2 * k);          // 8B-aligned
#pragma unroll
    for (int k = 0; k < 4; ++k)
      bq[k] = *(const float2*)(rp + BOX_BASE + 8 * l + 2 * k); // 8B-aligned
  }

  // single wait: covers global_load_lds (vmcnt) + all vector loads
  asm volatile("s_waitcnt vmcnt(0)" ::: "memory");
  __builtin_amdgcn_sched_barrier(0);

  const float* lab = (const float*)stw + loff;  // lab[25l + k]

  float acc = 0.0f;
  if (lane < L_CELLS) {
    const int l = lane;
    float c0v = cf.x, c1v = cf.y;
    float objf = lab[25 * l];

    // ---- branch-free: compute both paths, select ----
    float noobj_term = W_NOOBJ * (c0v * c0v + c1v * c1v);

    float bx[8] = {bq[0].x, bq[0].y, bq[1].x, bq[1].y,
                   bq[2].x, bq[2].y, bq[3].x, bq[3].y};
    float tx = lab[25 * l + 21], ty = lab[25 * l + 22];
    float tw = lab[25 * l + 23], th = lab[25 * l + 24];
    float t0 = tx * INV_S, t1 = ty * INV_S, t2 = tw, t3 = th;

    float iou[2], rmse2[2];
#pragma unroll
    for (int b = 0; b < 2; ++b) {
      float o0 = bx[4 * b + 0] * INV_S;
      float o1 = bx[4 * b + 1] * INV_S;
      float o2 = bx[4 * b + 2] * bx[4 * b + 2];
      float o3 = bx[4 * b + 3] * bx[4 * b + 3];
      float left = fmaxf(t0 - 0.5f * t2, o0 - 0.5f * o2);
      float right = fminf(t0 + 0.5f * t2, o0 + 0.5f * o2);
      float top = fmaxf(t1 - 0.5f * t3, o1 - 0.5f * o3);
      float bot = fminf(t1 + 0.5f * t3, o1 + 0.5f * o3);
      float wd = right - left;
      float h = bot - top;
      bool invalid = (wd < 0.0f) || (h < 0.0f);
      float inter = invalid ? 0.0f : wd * h;
      float uni = t2 * t3 + o2 * o3 - inter;
      iou[b] = invalid ? 0.0f : inter / fmaxf(uni, 1e-12f);
      float d0 = t0 - o0, d1 = t1 - o1, d2 = t2 - o2, d3 = t3 - o3;
      rmse2[b] = d0 * d0 + d1 * d1 + d2 * d2 + d3 * d3;  // sqrt monotone
    }

    float max_iou = fmaxf(iou[0], iou[1]);
    // jnp.argmax/argmin: first index wins ties -> strict compare for idx 1
    int best;
    if (max_iou > 0.0f)
      best = (iou[1] > iou[0]) ? 1 : 0;
    else
      best = (rmse2[1] < rmse2[0]) ? 1 : 0;
    float best_iou = iou[best];

    float cb = (best == 0) ? c0v : c1v;
    float co = (best == 0) ? c1v : c0v;
    float db = best_iou - cb;
    float obj_term = W_OBJ * db * db + W_NOOBJ * co * co;

    // cls: preds from regs (loaded above), tcls from staged labels
    float clsacc = 0.0f;
#pragma unroll
    for (int k = 0; k < 10; ++k) {
      float d0 = lab[25 * l + 1 + 2 * k] - pc[k].x;
      float d1 = lab[25 * l + 2 + 2 * k] - pc[k].y;
      clsacc += d0 * d0 + d1 * d1;
    }
    obj_term += W_CLS * clsacc;

    // coord: (tx, ty, sqrt(tw), sqrt(th)) vs best raw box
    float e0 = tx - bx[best * 4 + 0];
    float e1 = ty - bx[best * 4 + 1];
    float e2 = sqrtf(tw) - bx[best * 4 + 2];
    float e3 = sqrtf(th) - bx[best * 4 + 3];
    obj_term += W_COORD * (e0 * e0 + e1 * e1 + e2 * e2 + e3 * e3);

    acc = (objf != 0.0f) ? obj_term : noobj_term;
  }

  // ---- reduce: wave(64) shuffle -> LDS -> one ws slot per block ----
#pragma unroll
  for (int o = 32; o > 0; o >>= 1) acc += __shfl_down(acc, o);

  __shared__ float wsum[4];
  if (lane == 0) wsum[w] = acc;
  __syncthreads();
  if (tid == 0) ws[blockIdx.x] = wsum[0] + wsum[1] + wsum[2] + wsum[3];
}

__global__ __launch_bounds__(1024) void final_reduce_kernel(
    const float* __restrict__ ws, float* __restrict__ out, int m) {
  float acc = 0.0f;
  for (int i = threadIdx.x; i < m; i += 1024) acc += ws[i];
#pragma unroll
  for (int o = 32; o > 0; o >>= 1) acc += __shfl_down(acc, o);
  __shared__ float wsum[16];
  int wave = threadIdx.x >> 6;
  int lane = threadIdx.x & 63;
  if (lane == 0) wsum[wave] = acc;
  __syncthreads();
  if (threadIdx.x == 0) {
    float sum = 0.0f;
#pragma unroll
    for (int i = 0; i < 16; ++i) sum += wsum[i];
    out[0] = sum;
  }
}

extern "C" void kernel_launch(void* const* d_in, const int* in_sizes, int n_in,
                              void* d_out, int out_size, void* d_ws, size_t ws_size,
                              hipStream_t stream) {
  const float* preds = (const float*)d_in[0];
  const float* labels = (const float*)d_in[1];
  float* out = (float*)d_out;
  float* ws = (float*)d_ws;
  int n = in_sizes[0] / PRED_ROW;  // 16384
  int blocks = n / 4;              // 4096 (wave per sample)

  yolo_loss_kernel<<<blocks, 256, 0, stream>>>(preds, labels, ws);
  final_reduce_kernel<<<1, 1024, 0, stream>>>(ws, out, blocks);
}